// Round 2
// baseline (1079.776 us; speedup 1.0000x reference)
//
#include <hip/hip_runtime.h>

#define N_NODES 100000
#define N_EDGES 3200000
#define IN_DIM  512
#define HID_DIM 16

__device__ __forceinline__ void atomic_add_f32(float* p, float v) {
    __hip_atomic_fetch_add(p, v, __ATOMIC_RELAXED, __HIP_MEMORY_SCOPE_AGENT);
}
__device__ __forceinline__ int atomic_add_i32(int* p, int v) {
    return __hip_atomic_fetch_add(p, v, __ATOMIC_RELAXED, __HIP_MEMORY_SCOPE_AGENT);
}

// ---------------------------------------------------------------------------
// v2 path: coalesced wave-per-row GEMM + on-device CSR + gather-based spmm
// ---------------------------------------------------------------------------

// z0: zero the degree counters
__global__ void z0_zero(int* __restrict__ deg) {
    int i = blockIdx.x * blockDim.x + threadIdx.x;
    if (i < N_NODES) deg[i] = 0;
}

// g1: xw = x @ W1. One wave per row; K (512) split as 8 floats/lane;
// W1 fragment (8 k-rows x 16 j) lives in 128 VGPRs, loaded once per wave.
// x reads: 2 fully-coalesced dwordx4 per row (wave covers the 2KB row once).
__global__ __launch_bounds__(256) void g1_xw(const float* __restrict__ x,
                                             const float* __restrict__ W1,
                                             float* __restrict__ xw) {
    const int lane  = threadIdx.x & 63;
    const int wave  = (blockIdx.x * blockDim.x + threadIdx.x) >> 6;
    const int nwave = (gridDim.x * blockDim.x) >> 6;

    // W1 fragment: q=0..3 -> k=lane*4+q ; q=4..7 -> k=256+lane*4+(q-4)
    float w[8][16];
#pragma unroll
    for (int q = 0; q < 8; ++q) {
        int k = (q < 4) ? (lane * 4 + q) : (256 + lane * 4 + (q - 4));
        const float4* wr = (const float4*)(W1 + (size_t)k * HID_DIM);
        float4 a = wr[0], b = wr[1], c = wr[2], d = wr[3];
        w[q][0]=a.x; w[q][1]=a.y; w[q][2]=a.z; w[q][3]=a.w;
        w[q][4]=b.x; w[q][5]=b.y; w[q][6]=b.z; w[q][7]=b.w;
        w[q][8]=c.x; w[q][9]=c.y; w[q][10]=c.z; w[q][11]=c.w;
        w[q][12]=d.x; w[q][13]=d.y; w[q][14]=d.z; w[q][15]=d.w;
    }

    const float4* x4 = (const float4*)x;  // row stride 128 float4s
    int row = wave;
    float4 xa, xb;
    if (row < N_NODES) {
        xa = x4[(size_t)row * 128 + lane];        // k = lane*4 .. +3
        xb = x4[(size_t)row * 128 + 64 + lane];   // k = 256 + lane*4 .. +3
    }
    while (row < N_NODES) {
        int nrow = row + nwave;
        float4 na, nb;
        if (nrow < N_NODES) {   // prefetch next row before the compute chain
            na = x4[(size_t)nrow * 128 + lane];
            nb = x4[(size_t)nrow * 128 + 64 + lane];
        }
        float acc[16];
#pragma unroll
        for (int j = 0; j < 16; ++j) {
            acc[j] = xa.x * w[0][j] + xa.y * w[1][j] + xa.z * w[2][j] + xa.w * w[3][j]
                   + xb.x * w[4][j] + xb.y * w[5][j] + xb.z * w[6][j] + xb.w * w[7][j];
        }
        // reduce across 64 lanes; lane l (mod 16) ends with output j = l&15
#pragma unroll
        for (int j = 0; j < 16; ++j) {
            acc[j] += __shfl_xor(acc[j], 32);
            acc[j] += __shfl_xor(acc[j], 16);
        }
        float c8[8];
#pragma unroll
        for (int i = 0; i < 8; ++i) {
            bool hi = (lane & 8) != 0;
            float keep = hi ? acc[i + 8] : acc[i];
            float send = hi ? acc[i] : acc[i + 8];
            c8[i] = keep + __shfl_xor(send, 8);
        }
        float c4[4];
#pragma unroll
        for (int i = 0; i < 4; ++i) {
            bool hi = (lane & 4) != 0;
            float keep = hi ? c8[i + 4] : c8[i];
            float send = hi ? c8[i] : c8[i + 4];
            c4[i] = keep + __shfl_xor(send, 4);
        }
        float c2[2];
#pragma unroll
        for (int i = 0; i < 2; ++i) {
            bool hi = (lane & 2) != 0;
            float keep = hi ? c4[i + 2] : c4[i];
            float send = hi ? c4[i] : c4[i + 2];
            c2[i] = keep + __shfl_xor(send, 2);
        }
        {
            bool hi = (lane & 1) != 0;
            float keep = hi ? c2[1] : c2[0];
            float send = hi ? c2[0] : c2[1];
            float c1 = keep + __shfl_xor(send, 1);
            if (lane < 16) xw[(size_t)row * HID_DIM + lane] = c1;
        }
        row = nrow; xa = na; xb = nb;
    }
}

// hA: in-degree histogram
__global__ void hA_hist(const int* __restrict__ dst, int* __restrict__ deg) {
    int e = blockIdx.x * blockDim.x + threadIdx.x;
    if (e < N_EDGES) atomic_add_i32(&deg[dst[e]], 1);
}

// hB: exclusive scan of deg -> row_ptr (+ cursor copy). Single block of 1024.
__global__ __launch_bounds__(1024) void hB_scan(const int* __restrict__ deg,
                                                int* __restrict__ row_ptr,
                                                int* __restrict__ cursor) {
    __shared__ int part[1024];
    const int t = threadIdx.x;
    const int CH = 98;                      // 98*1024 >= 100000
    int lo = t * CH, hi = min(lo + CH, N_NODES);
    int s = 0;
    for (int i = lo; i < hi; ++i) s += deg[i];
    part[t] = s;
    __syncthreads();
    for (int off = 1; off < 1024; off <<= 1) {
        int u = (t >= off) ? part[t - off] : 0;
        __syncthreads();
        part[t] += u;
        __syncthreads();
    }
    int run = part[t] - s;                  // exclusive prefix
    for (int i = lo; i < hi; ++i) {
        row_ptr[i] = run; cursor[i] = run; run += deg[i];
    }
    if (t == 1023) row_ptr[N_NODES] = part[1023];
}

// hC: scatter edges into CSR slots as packed (w:hi32, src:lo32) records
__global__ void hC_scatter(const int* __restrict__ src, const int* __restrict__ dst,
                           const float* __restrict__ wgt, int* __restrict__ cursor,
                           unsigned long long* __restrict__ rec) {
    int e = blockIdx.x * blockDim.x + threadIdx.x;
    if (e < N_EDGES) {
        int s = src[e], d = dst[e];
        float w = wgt[e];
        int pos = atomic_add_i32(&cursor[d], 1);
        rec[pos] = ((unsigned long long)__float_as_uint(w) << 32) | (unsigned)s;
    }
}

// sD: fused spmm1 + bias + relu + (.W2): 16 lanes per node.
// Gather xw[src][0:16] = 64B contiguous per group; accumulate in regs.
__global__ __launch_bounds__(256) void sD_layer1(const int* __restrict__ row_ptr,
                                                 const unsigned long long* __restrict__ rec,
                                                 const float* __restrict__ xw,
                                                 const float* __restrict__ b1,
                                                 const float* __restrict__ W2,
                                                 float* __restrict__ hw) {
    const int g = threadIdx.x >> 4;
    const int j = threadIdx.x & 15;
    const int node = blockIdx.x * 16 + g;          // grid sized exactly
    int e0 = row_ptr[node], e1 = row_ptr[node + 1];
    float acc = 0.0f;
    for (int e = e0; e < e1; ++e) {
        unsigned long long r = rec[e];
        float w = __uint_as_float((unsigned)(r >> 32));
        int   s = (int)(unsigned)(r & 0xffffffffu);
        acc += w * xw[(size_t)s * HID_DIM + j];
    }
    float v = fmaxf(acc + b1[j], 0.0f) * W2[j];
    v += __shfl_xor(v, 1);
    v += __shfl_xor(v, 2);
    v += __shfl_xor(v, 4);
    v += __shfl_xor(v, 8);
    if (j == 0) hw[node] = v;
}

// sE: spmm2 via same CSR: out[n] = b2 + sum w * hw[src]; 8 lanes per node
__global__ __launch_bounds__(256) void sE_layer2(const int* __restrict__ row_ptr,
                                                 const unsigned long long* __restrict__ rec,
                                                 const float* __restrict__ hw,
                                                 const float* __restrict__ b2,
                                                 float* __restrict__ out) {
    const int t = blockIdx.x * blockDim.x + threadIdx.x;
    const int node = t >> 3;
    const int i = t & 7;
    if (node >= N_NODES) return;
    int e0 = row_ptr[node], e1 = row_ptr[node + 1];
    float s = 0.0f;
    for (int e = e0 + i; e < e1; e += 8) {
        unsigned long long r = rec[e];
        s += __uint_as_float((unsigned)(r >> 32)) * hw[r & 0xffffffffu];
    }
    s += __shfl_xor(s, 1);
    s += __shfl_xor(s, 2);
    s += __shfl_xor(s, 4);
    if (i == 0) out[node] = b2[0] + s;
}

// ---------------------------------------------------------------------------
// v1 fallback path (round-1 kernels) — used only if ws_size is too small
// ---------------------------------------------------------------------------

__global__ void k0_init(const float* __restrict__ W1, const float* __restrict__ b2,
                        float* __restrict__ W1T, float* __restrict__ h,
                        float* __restrict__ out) {
    int i = blockIdx.x * blockDim.x + threadIdx.x;
    if (i < N_NODES * HID_DIM) h[i] = 0.0f;
    if (i < N_NODES) out[i] = b2[0];
    if (i < IN_DIM * HID_DIM) {
        int j = i & (HID_DIM - 1);
        int k = i >> 4;
        W1T[j * IN_DIM + k] = W1[i];
    }
}

__global__ void k1_xw(const float4* __restrict__ x4, const float4* __restrict__ w1t4,
                      float2* __restrict__ xw2) {
    int t = blockIdx.x * blockDim.x + threadIdx.x;
    int j2  = t & 7;
    int row = t >> 3;
    const float4* __restrict__ xr = x4   + (size_t)row * (IN_DIM / 4);
    const float4* __restrict__ wa = w1t4 + (size_t)(2 * j2)     * (IN_DIM / 4);
    const float4* __restrict__ wb = w1t4 + (size_t)(2 * j2 + 1) * (IN_DIM / 4);
    float a0 = 0.0f, a1 = 0.0f;
#pragma unroll 8
    for (int k = 0; k < IN_DIM / 4; ++k) {
        float4 xv = xr[k]; float4 w0 = wa[k]; float4 w1 = wb[k];
        a0 += xv.x * w0.x + xv.y * w0.y + xv.z * w0.z + xv.w * w0.w;
        a1 += xv.x * w1.x + xv.y * w1.y + xv.z * w1.z + xv.w * w1.w;
    }
    xw2[(size_t)row * 8 + j2] = make_float2(a0, a1);
}

__global__ void k2_spmm1(const int* __restrict__ src, const int* __restrict__ dst,
                         const float* __restrict__ wgt, const float* __restrict__ xw,
                         float* __restrict__ h) {
    int t = blockIdx.x * blockDim.x + threadIdx.x;
    int e = t >> 4;
    int j = t & (HID_DIM - 1);
    if (e < N_EDGES) {
        int s = src[e], d = dst[e];
        float v = wgt[e] * xw[(size_t)s * HID_DIM + j];
        atomic_add_f32(&h[(size_t)d * HID_DIM + j], v);
    }
}

__global__ void k3_act(const float* __restrict__ h, const float* __restrict__ b1,
                       const float* __restrict__ W2, float* __restrict__ hw) {
    int i = blockIdx.x * blockDim.x + threadIdx.x;
    if (i >= N_NODES) return;
    const float4* __restrict__ h4 = (const float4*)(h + (size_t)i * HID_DIM);
    const float4* __restrict__ b4 = (const float4*)b1;
    const float4* __restrict__ w4 = (const float4*)W2;
    float acc = 0.0f;
#pragma unroll
    for (int q = 0; q < HID_DIM / 4; ++q) {
        float4 hv = h4[q]; float4 bv = b4[q]; float4 wv = w4[q];
        acc += fmaxf(hv.x + bv.x, 0.0f) * wv.x;
        acc += fmaxf(hv.y + bv.y, 0.0f) * wv.y;
        acc += fmaxf(hv.z + bv.z, 0.0f) * wv.z;
        acc += fmaxf(hv.w + bv.w, 0.0f) * wv.w;
    }
    hw[i] = acc;
}

__global__ void k4_spmm2(const int* __restrict__ src, const int* __restrict__ dst,
                         const float* __restrict__ wgt, const float* __restrict__ hw,
                         float* __restrict__ out) {
    int e = blockIdx.x * blockDim.x + threadIdx.x;
    if (e < N_EDGES) {
        atomic_add_f32(&out[dst[e]], wgt[e] * hw[src[e]]);
    }
}

// ---------------------------------------------------------------------------

extern "C" void kernel_launch(void* const* d_in, const int* in_sizes, int n_in,
                              void* d_out, int out_size, void* d_ws, size_t ws_size,
                              hipStream_t stream) {
    const float* x    = (const float*)d_in[0];
    const int*   esrc = (const int*)  d_in[1];
    const int*   edst = (const int*)  d_in[2];
    const float* ew   = (const float*)d_in[3];
    const float* W1   = (const float*)d_in[4];
    const float* b1   = (const float*)d_in[5];
    const float* W2   = (const float*)d_in[6];
    const float* b2   = (const float*)d_in[7];
    float* out = (float*)d_out;
    char* ws = (char*)d_ws;

    // v2 workspace layout
    float* xw      = (float*)ws;                                  // N*16
    float* hw      = xw + (size_t)N_NODES * HID_DIM;              // N
    int*   deg     = (int*)(hw + N_NODES);                        // N
    int*   row_ptr = deg + N_NODES;                               // N+1
    int*   cursor  = row_ptr + N_NODES + 1;                       // N
    size_t rec_off = (((size_t)((char*)(cursor + N_NODES) - ws)) + 7) & ~(size_t)7;
    unsigned long long* rec = (unsigned long long*)(ws + rec_off);
    size_t need = rec_off + (size_t)N_EDGES * 8;

    if (ws_size >= need) {
        z0_zero<<<(N_NODES + 255) / 256, 256, 0, stream>>>(deg);
        g1_xw<<<640, 256, 0, stream>>>(x, W1, xw);
        hA_hist<<<(N_EDGES + 255) / 256, 256, 0, stream>>>(edst, deg);
        hB_scan<<<1, 1024, 0, stream>>>(deg, row_ptr, cursor);
        hC_scatter<<<(N_EDGES + 255) / 256, 256, 0, stream>>>(esrc, edst, ew, cursor, rec);
        sD_layer1<<<N_NODES / 16, 256, 0, stream>>>(row_ptr, rec, xw, b1, W2, hw);
        sE_layer2<<<(N_NODES * 8) / 256, 256, 0, stream>>>(row_ptr, rec, hw, b2, out);
    } else {
        // fallback: round-1 structure
        float* f_xw  = (float*)ws;
        float* f_h   = f_xw + (size_t)N_NODES * HID_DIM;
        float* f_hw  = f_h  + (size_t)N_NODES * HID_DIM;
        float* f_W1T = f_hw + N_NODES;
        int n = N_NODES * HID_DIM;
        k0_init<<<(n + 255) / 256, 256, 0, stream>>>(W1, b2, f_W1T, f_h, out);
        k1_xw<<<(N_NODES * 8) / 256, 256, 0, stream>>>(
            (const float4*)x, (const float4*)f_W1T, (float2*)f_xw);
        k2_spmm1<<<(N_EDGES * 16) / 256, 256, 0, stream>>>(esrc, edst, ew, f_xw, f_h);
        k3_act<<<(N_NODES + 255) / 256, 256, 0, stream>>>(f_h, b1, W2, f_hw);
        k4_spmm2<<<(N_EDGES + 255) / 256, 256, 0, stream>>>(esrc, edst, ew, f_hw, out);
    }
}

// Round 3
// 823.575 us; speedup vs baseline: 1.3111x; 1.3111x over previous
//
#include <hip/hip_runtime.h>

#define N_NODES 100000
#define N_EDGES 3200000
#define IN_DIM  512
#define HID_DIM 16

#define B_BKT   782      // ceil(100000 / 128) buckets of 128 nodes
#define BKT_SH  7        // bucket = dst >> 7, dstrel = dst & 127
#define EPB     12500    // edges per scatter block (256 blocks * 12500 = 3.2M)
#define CAP_MAX 4608     // per-bucket record capacity (mean 4093 + ~8 sigma)

__device__ __forceinline__ void atomic_add_f32(float* p, float v) {
    __hip_atomic_fetch_add(p, v, __ATOMIC_RELAXED, __HIP_MEMORY_SCOPE_AGENT);
}
__device__ __forceinline__ int atomic_add_i32(int* p, int v) {
    return __hip_atomic_fetch_add(p, v, __ATOMIC_RELAXED, __HIP_MEMORY_SCOPE_AGENT);
}

// ---------------------------------------------------------------------------
// z0: init per-bucket cursors to region starts
__global__ void z0_init(int* __restrict__ cursor, int cap) {
    int b = blockIdx.x * blockDim.x + threadIdx.x;
    if (b < B_BKT) cursor[b] = b * cap;
}

// ---------------------------------------------------------------------------
// g1: xw = x @ W1. One wave per row; W1 fragment in 128 VGPRs; x reads are
// two fully-coalesced dwordx4 per row (wave covers the 2KB row exactly once).
__global__ __launch_bounds__(256) void g1_xw(const float* __restrict__ x,
                                             const float* __restrict__ W1,
                                             float* __restrict__ xw) {
    const int lane  = threadIdx.x & 63;
    const int wave  = (blockIdx.x * blockDim.x + threadIdx.x) >> 6;
    const int nwave = (gridDim.x * blockDim.x) >> 6;

    float w[8][16];
#pragma unroll
    for (int q = 0; q < 8; ++q) {
        int k = (q < 4) ? (lane * 4 + q) : (256 + lane * 4 + (q - 4));
        const float4* wr = (const float4*)(W1 + (size_t)k * HID_DIM);
        float4 a = wr[0], b = wr[1], c = wr[2], d = wr[3];
        w[q][0]=a.x; w[q][1]=a.y; w[q][2]=a.z; w[q][3]=a.w;
        w[q][4]=b.x; w[q][5]=b.y; w[q][6]=b.z; w[q][7]=b.w;
        w[q][8]=c.x; w[q][9]=c.y; w[q][10]=c.z; w[q][11]=c.w;
        w[q][12]=d.x; w[q][13]=d.y; w[q][14]=d.z; w[q][15]=d.w;
    }

    const float4* x4 = (const float4*)x;
    int row = wave;
    float4 xa, xb;
    if (row < N_NODES) {
        xa = x4[(size_t)row * 128 + lane];
        xb = x4[(size_t)row * 128 + 64 + lane];
    }
    while (row < N_NODES) {
        int nrow = row + nwave;
        float4 na, nb;
        if (nrow < N_NODES) {
            na = x4[(size_t)nrow * 128 + lane];
            nb = x4[(size_t)nrow * 128 + 64 + lane];
        }
        float acc[16];
#pragma unroll
        for (int j = 0; j < 16; ++j) {
            acc[j] = xa.x * w[0][j] + xa.y * w[1][j] + xa.z * w[2][j] + xa.w * w[3][j]
                   + xb.x * w[4][j] + xb.y * w[5][j] + xb.z * w[6][j] + xb.w * w[7][j];
        }
#pragma unroll
        for (int j = 0; j < 16; ++j) {
            acc[j] += __shfl_xor(acc[j], 32);
            acc[j] += __shfl_xor(acc[j], 16);
        }
        float c8[8];
#pragma unroll
        for (int i = 0; i < 8; ++i) {
            bool hi = (lane & 8) != 0;
            float keep = hi ? acc[i + 8] : acc[i];
            float send = hi ? acc[i] : acc[i + 8];
            c8[i] = keep + __shfl_xor(send, 8);
        }
        float c4[4];
#pragma unroll
        for (int i = 0; i < 4; ++i) {
            bool hi = (lane & 4) != 0;
            float keep = hi ? c8[i + 4] : c8[i];
            float send = hi ? c8[i] : c8[i + 4];
            c4[i] = keep + __shfl_xor(send, 4);
        }
        float c2[2];
#pragma unroll
        for (int i = 0; i < 2; ++i) {
            bool hi = (lane & 2) != 0;
            float keep = hi ? c4[i + 2] : c4[i];
            float send = hi ? c4[i] : c4[i + 2];
            c2[i] = keep + __shfl_xor(send, 2);
        }
        {
            bool hi = (lane & 1) != 0;
            float keep = hi ? c2[1] : c2[0];
            float send = hi ? c2[0] : c2[1];
            float c1 = keep + __shfl_xor(send, 1);
            if (lane < 16) xw[(size_t)row * HID_DIM + lane] = c1;
        }
        row = nrow; xa = na; xb = nb;
    }
}

// ---------------------------------------------------------------------------
// s1: counting-sort edges into 782 bucket regions, block-batched reservation.
// Each run of records is written by exactly one block -> one XCD L2.
__global__ __launch_bounds__(256) void s1_bin(const int* __restrict__ src,
                                              const int* __restrict__ dst,
                                              const float* __restrict__ wgt,
                                              int* __restrict__ cursor,
                                              uint2* __restrict__ rec, int cap) {
    __shared__ int hist[B_BKT];
    __shared__ int base[B_BKT];
    const int t = threadIdx.x;
    for (int b = t; b < B_BKT; b += 256) hist[b] = 0;
    __syncthreads();
    const int e0 = blockIdx.x * EPB;
    const int e1 = min(e0 + EPB, N_EDGES);
    for (int e = e0 + t; e < e1; e += 256)
        atomicAdd(&hist[dst[e] >> BKT_SH], 1);
    __syncthreads();
    for (int b = t; b < B_BKT; b += 256) {
        int c = hist[b];
        base[b] = c > 0 ? atomic_add_i32(&cursor[b], c) : 0;
    }
    __syncthreads();
    for (int b = t; b < B_BKT; b += 256) hist[b] = 0;
    __syncthreads();
    for (int e = e0 + t; e < e1; e += 256) {
        int d = dst[e];
        int b = d >> BKT_SH;
        int pos = base[b] + atomicAdd(&hist[b], 1);
        rec[pos] = make_uint2(((unsigned)src[e] << BKT_SH) | (unsigned)(d & 127),
                              __float_as_uint(wgt[e]));
    }
}

// ---------------------------------------------------------------------------
// p4: fused spmm1 + bias + relu + (.W2). One block per bucket; h slice in LDS.
// 16 j-lanes per edge: xw gather is one 64B line per edge; ds_add_f32 accum.
__global__ __launch_bounds__(256) void p4_layer1(const int* __restrict__ cursor,
                                                 const uint2* __restrict__ rec,
                                                 const float* __restrict__ xw,
                                                 const float* __restrict__ b1,
                                                 const float* __restrict__ W2,
                                                 float* __restrict__ hw, int cap) {
    __shared__ float hloc[128 * 16];
    const int t = threadIdx.x;
    const int bkt = blockIdx.x;
    for (int i = t; i < 128 * 16; i += 256) hloc[i] = 0.0f;
    __syncthreads();
    const int e0 = bkt * cap;
    const int cnt = cursor[bkt] - e0;
    const int slot = t >> 4, j = t & 15;
    for (int i = slot; i < cnt; i += 16) {
        uint2 r = rec[e0 + i];
        float w = __uint_as_float(r.y);
        int srcn = (int)(r.x >> BKT_SH);
        int dr   = (int)(r.x & 127u);
        atomicAdd(&hloc[dr * 16 + j], w * xw[(size_t)srcn * HID_DIM + j]);
    }
    __syncthreads();
    const float b1j = b1[j], w2j = W2[j];
    const int node0 = bkt << BKT_SH;
    for (int n = slot; n < 128; n += 16) {
        int g = node0 + n;
        float v = fmaxf(hloc[n * 16 + j] + b1j, 0.0f) * w2j;
        v += __shfl_xor(v, 1);
        v += __shfl_xor(v, 2);
        v += __shfl_xor(v, 4);
        v += __shfl_xor(v, 8);
        if (j == 0 && g < N_NODES) hw[g] = v;
    }
}

// ---------------------------------------------------------------------------
// p5: spmm2 over the same sorted records; out slice (128 floats) in LDS.
__global__ __launch_bounds__(256) void p5_layer2(const int* __restrict__ cursor,
                                                 const uint2* __restrict__ rec,
                                                 const float* __restrict__ hw,
                                                 const float* __restrict__ b2,
                                                 float* __restrict__ out, int cap) {
    __shared__ float oloc[128];
    const int t = threadIdx.x;
    const int bkt = blockIdx.x;
    if (t < 128) oloc[t] = 0.0f;
    __syncthreads();
    const int e0 = bkt * cap;
    const int cnt = cursor[bkt] - e0;
    for (int i = t; i < cnt; i += 256) {
        uint2 r = rec[e0 + i];
        atomicAdd(&oloc[r.x & 127u], __uint_as_float(r.y) * hw[r.x >> BKT_SH]);
    }
    __syncthreads();
    if (t < 128) {
        int g = (bkt << BKT_SH) + t;
        if (g < N_NODES) out[g] = b2[0] + oloc[t];
    }
}

// ---------------------------------------------------------------------------
// fallback path (round-1 style atomic scatter) if workspace is too small
// ---------------------------------------------------------------------------
__global__ void f0_zero(float* __restrict__ h, const float* __restrict__ b2,
                        float* __restrict__ out) {
    int i = blockIdx.x * blockDim.x + threadIdx.x;
    if (i < N_NODES * HID_DIM) h[i] = 0.0f;
    if (i < N_NODES) out[i] = b2[0];
}
__global__ void k2_spmm1(const int* __restrict__ src, const int* __restrict__ dst,
                         const float* __restrict__ wgt, const float* __restrict__ xw,
                         float* __restrict__ h) {
    int t = blockIdx.x * blockDim.x + threadIdx.x;
    int e = t >> 4;
    int j = t & (HID_DIM - 1);
    if (e < N_EDGES) {
        float v = wgt[e] * xw[(size_t)src[e] * HID_DIM + j];
        atomic_add_f32(&h[(size_t)dst[e] * HID_DIM + j], v);
    }
}
__global__ void k3_act(const float* __restrict__ h, const float* __restrict__ b1,
                       const float* __restrict__ W2, float* __restrict__ hw) {
    int i = blockIdx.x * blockDim.x + threadIdx.x;
    if (i >= N_NODES) return;
    const float4* h4 = (const float4*)(h + (size_t)i * HID_DIM);
    const float4* b4 = (const float4*)b1;
    const float4* w4 = (const float4*)W2;
    float acc = 0.0f;
#pragma unroll
    for (int q = 0; q < HID_DIM / 4; ++q) {
        float4 hv = h4[q]; float4 bv = b4[q]; float4 wv = w4[q];
        acc += fmaxf(hv.x + bv.x, 0.0f) * wv.x;
        acc += fmaxf(hv.y + bv.y, 0.0f) * wv.y;
        acc += fmaxf(hv.z + bv.z, 0.0f) * wv.z;
        acc += fmaxf(hv.w + bv.w, 0.0f) * wv.w;
    }
    hw[i] = acc;
}
__global__ void k4_spmm2(const int* __restrict__ src, const int* __restrict__ dst,
                         const float* __restrict__ wgt, const float* __restrict__ hw,
                         float* __restrict__ out) {
    int e = blockIdx.x * blockDim.x + threadIdx.x;
    if (e < N_EDGES) atomic_add_f32(&out[dst[e]], wgt[e] * hw[src[e]]);
}

// ---------------------------------------------------------------------------

extern "C" void kernel_launch(void* const* d_in, const int* in_sizes, int n_in,
                              void* d_out, int out_size, void* d_ws, size_t ws_size,
                              hipStream_t stream) {
    const float* x    = (const float*)d_in[0];
    const int*   esrc = (const int*)  d_in[1];
    const int*   edst = (const int*)  d_in[2];
    const float* ew   = (const float*)d_in[3];
    const float* W1   = (const float*)d_in[4];
    const float* b1   = (const float*)d_in[5];
    const float* W2   = (const float*)d_in[6];
    const float* b2   = (const float*)d_in[7];
    float* out = (float*)d_out;
    char* ws = (char*)d_ws;

    // workspace layout
    float* xw     = (float*)ws;                               // N*16 floats
    float* hw     = xw + (size_t)N_NODES * HID_DIM;           // N floats
    int*   cursor = (int*)(hw + N_NODES);                     // B_BKT ints
    size_t rec_off = ((size_t)((char*)(cursor + B_BKT) - ws) + 15) & ~(size_t)15;
    uint2* rec = (uint2*)(ws + rec_off);

    int cap = 0;
    if (ws_size > rec_off) {
        size_t cap_fit = (ws_size - rec_off) / ((size_t)B_BKT * sizeof(uint2));
        cap = (int)(cap_fit < CAP_MAX ? cap_fit : CAP_MAX);
    }

    if (cap >= 4480) {
        z0_init<<<(B_BKT + 255) / 256, 256, 0, stream>>>(cursor, cap);
        g1_xw<<<640, 256, 0, stream>>>(x, W1, xw);
        s1_bin<<<N_EDGES / EPB, 256, 0, stream>>>(esrc, edst, ew, cursor, rec, cap);
        p4_layer1<<<B_BKT, 256, 0, stream>>>(cursor, rec, xw, b1, W2, hw, cap);
        p5_layer2<<<B_BKT, 256, 0, stream>>>(cursor, rec, hw, b2, out, cap);
    } else {
        // fallback: atomic scatter (needs xw + h + hw only)
        float* f_xw = (float*)ws;
        float* f_h  = f_xw + (size_t)N_NODES * HID_DIM;
        float* f_hw = f_h  + (size_t)N_NODES * HID_DIM;
        int n = N_NODES * HID_DIM;
        f0_zero<<<(n + 255) / 256, 256, 0, stream>>>(f_h, b2, out);
        g1_xw<<<640, 256, 0, stream>>>(x, W1, f_xw);
        k2_spmm1<<<(N_EDGES * 16) / 256, 256, 0, stream>>>(esrc, edst, ew, f_xw, f_h);
        k3_act<<<(N_NODES + 255) / 256, 256, 0, stream>>>(f_h, b1, W2, f_hw);
        k4_spmm2<<<(N_EDGES + 255) / 256, 256, 0, stream>>>(esrc, edst, ew, f_hw, out);
    }
}

// Round 4
// 805.596 us; speedup vs baseline: 1.3403x; 1.0223x over previous
//
#include <hip/hip_runtime.h>
#include <hip/hip_fp16.h>

#define N_NODES 100000
#define N_EDGES 3200000
#define IN_DIM  512
#define HID_DIM 16

#define B_BKT   782      // ceil(100000 / 128) buckets of 128 nodes
#define BKT_SH  7        // bucket = dst >> 7, dstrel = dst & 127
#define EPB     12500    // edges per scatter block (256 blocks * 12500 = 3.2M)
#define CAP_MAX 4608     // per-bucket record capacity (mean 4093 + ~8 sigma)
#define HSTRIDE 17       // padded LDS stride: 17*dr mod 32 spreads banks

__device__ __forceinline__ void atomic_add_f32(float* p, float v) {
    __hip_atomic_fetch_add(p, v, __ATOMIC_RELAXED, __HIP_MEMORY_SCOPE_AGENT);
}
__device__ __forceinline__ int atomic_add_i32(int* p, int v) {
    return __hip_atomic_fetch_add(p, v, __ATOMIC_RELAXED, __HIP_MEMORY_SCOPE_AGENT);
}

// ---------------------------------------------------------------------------
__global__ void z0_init(int* __restrict__ cursor, int cap) {
    int b = blockIdx.x * blockDim.x + threadIdx.x;
    if (b < B_BKT) cursor[b] = b * cap;
}

// ---------------------------------------------------------------------------
// g1: xw = x @ W1 -> fp16. One wave per row; W1 fragment in 128 VGPRs;
// x reads are two fully-coalesced dwordx4 per row.
__global__ __launch_bounds__(256) void g1_xw(const float* __restrict__ x,
                                             const float* __restrict__ W1,
                                             __half* __restrict__ xwh) {
    const int lane  = threadIdx.x & 63;
    const int wave  = (blockIdx.x * blockDim.x + threadIdx.x) >> 6;
    const int nwave = (gridDim.x * blockDim.x) >> 6;

    float w[8][16];
#pragma unroll
    for (int q = 0; q < 8; ++q) {
        int k = (q < 4) ? (lane * 4 + q) : (256 + lane * 4 + (q - 4));
        const float4* wr = (const float4*)(W1 + (size_t)k * HID_DIM);
        float4 a = wr[0], b = wr[1], c = wr[2], d = wr[3];
        w[q][0]=a.x; w[q][1]=a.y; w[q][2]=a.z; w[q][3]=a.w;
        w[q][4]=b.x; w[q][5]=b.y; w[q][6]=b.z; w[q][7]=b.w;
        w[q][8]=c.x; w[q][9]=c.y; w[q][10]=c.z; w[q][11]=c.w;
        w[q][12]=d.x; w[q][13]=d.y; w[q][14]=d.z; w[q][15]=d.w;
    }

    const float4* x4 = (const float4*)x;
    int row = wave;
    float4 xa, xb;
    if (row < N_NODES) {
        xa = x4[(size_t)row * 128 + lane];
        xb = x4[(size_t)row * 128 + 64 + lane];
    }
    while (row < N_NODES) {
        int nrow = row + nwave;
        float4 na, nb;
        if (nrow < N_NODES) {
            na = x4[(size_t)nrow * 128 + lane];
            nb = x4[(size_t)nrow * 128 + 64 + lane];
        }
        float acc[16];
#pragma unroll
        for (int j = 0; j < 16; ++j) {
            acc[j] = xa.x * w[0][j] + xa.y * w[1][j] + xa.z * w[2][j] + xa.w * w[3][j]
                   + xb.x * w[4][j] + xb.y * w[5][j] + xb.z * w[6][j] + xb.w * w[7][j];
        }
#pragma unroll
        for (int j = 0; j < 16; ++j) {
            acc[j] += __shfl_xor(acc[j], 32);
            acc[j] += __shfl_xor(acc[j], 16);
        }
        float c8[8];
#pragma unroll
        for (int i = 0; i < 8; ++i) {
            bool hi = (lane & 8) != 0;
            float keep = hi ? acc[i + 8] : acc[i];
            float send = hi ? acc[i] : acc[i + 8];
            c8[i] = keep + __shfl_xor(send, 8);
        }
        float c4[4];
#pragma unroll
        for (int i = 0; i < 4; ++i) {
            bool hi = (lane & 4) != 0;
            float keep = hi ? c8[i + 4] : c8[i];
            float send = hi ? c8[i] : c8[i + 4];
            c4[i] = keep + __shfl_xor(send, 4);
        }
        float c2[2];
#pragma unroll
        for (int i = 0; i < 2; ++i) {
            bool hi = (lane & 2) != 0;
            float keep = hi ? c4[i + 2] : c4[i];
            float send = hi ? c4[i] : c4[i + 2];
            c2[i] = keep + __shfl_xor(send, 2);
        }
        {
            bool hi = (lane & 1) != 0;
            float keep = hi ? c2[1] : c2[0];
            float send = hi ? c2[0] : c2[1];
            float c1 = keep + __shfl_xor(send, 1);
            if (lane < 16) xwh[(size_t)row * HID_DIM + lane] = __float2half_rn(c1);
        }
        row = nrow; xa = na; xb = nb;
    }
}

// ---------------------------------------------------------------------------
// s1: counting-sort edges into bucket regions, block-batched reservation,
// int4-vectorized passes.
__global__ __launch_bounds__(256) void s1_bin(const int* __restrict__ src,
                                              const int* __restrict__ dst,
                                              const float* __restrict__ wgt,
                                              int* __restrict__ cursor,
                                              uint2* __restrict__ rec, int cap) {
    __shared__ int hist[B_BKT];
    __shared__ int base[B_BKT];
    const int t = threadIdx.x;
    for (int b = t; b < B_BKT; b += 256) hist[b] = 0;
    __syncthreads();
    const int e0 = blockIdx.x * EPB;          // EPB*256 == N_EDGES exactly
    const int4*   d4 = (const int4*)(dst + e0);
    const int4*   s4 = (const int4*)(src + e0);
    const float4* w4 = (const float4*)(wgt + e0);
    const int NG = EPB / 4;                   // 3125 int4 groups
    for (int g = t; g < NG; g += 256) {
        int4 d = d4[g];
        atomicAdd(&hist[d.x >> BKT_SH], 1);
        atomicAdd(&hist[d.y >> BKT_SH], 1);
        atomicAdd(&hist[d.z >> BKT_SH], 1);
        atomicAdd(&hist[d.w >> BKT_SH], 1);
    }
    __syncthreads();
    for (int b = t; b < B_BKT; b += 256) {
        int c = hist[b];
        base[b] = c > 0 ? atomic_add_i32(&cursor[b], c) : 0;
    }
    __syncthreads();
    for (int b = t; b < B_BKT; b += 256) hist[b] = 0;
    __syncthreads();
    for (int g = t; g < NG; g += 256) {
        int4 d = d4[g];
        int4 s = s4[g];
        float4 w = w4[g];
        {
            int b = d.x >> BKT_SH;
            int pos = base[b] + atomicAdd(&hist[b], 1);
            rec[pos] = make_uint2(((unsigned)s.x << BKT_SH) | (unsigned)(d.x & 127),
                                  __float_as_uint(w.x));
        }
        {
            int b = d.y >> BKT_SH;
            int pos = base[b] + atomicAdd(&hist[b], 1);
            rec[pos] = make_uint2(((unsigned)s.y << BKT_SH) | (unsigned)(d.y & 127),
                                  __float_as_uint(w.y));
        }
        {
            int b = d.z >> BKT_SH;
            int pos = base[b] + atomicAdd(&hist[b], 1);
            rec[pos] = make_uint2(((unsigned)s.z << BKT_SH) | (unsigned)(d.z & 127),
                                  __float_as_uint(w.z));
        }
        {
            int b = d.w >> BKT_SH;
            int pos = base[b] + atomicAdd(&hist[b], 1);
            rec[pos] = make_uint2(((unsigned)s.w << BKT_SH) | (unsigned)(d.w & 127),
                                  __float_as_uint(w.w));
        }
    }
}

// ---------------------------------------------------------------------------
// p4: fused spmm1 + bias + relu + (.W2). One block per bucket; padded h slice
// in LDS. 4 lanes per edge (uint2 = 4 fp16), 64 edge-slots per block,
// 4x unroll -> ~8 loads in flight per thread.
__global__ __launch_bounds__(256) void p4_layer1(const int* __restrict__ cursor,
                                                 const uint2* __restrict__ rec,
                                                 const uint2* __restrict__ xwh,
                                                 const float* __restrict__ b1,
                                                 const float* __restrict__ W2,
                                                 float* __restrict__ hw, int cap) {
    __shared__ float hloc[128 * HSTRIDE];
    const int t = threadIdx.x;
    const int bkt = blockIdx.x;
    for (int i = t; i < 128 * HSTRIDE; i += 256) hloc[i] = 0.0f;
    __syncthreads();
    const int e0 = bkt * cap;
    const int cnt = cursor[bkt] - e0;
    const int slot = t >> 2;      // 0..63
    const int l    = t & 3;       // which fp16 quad (j = 4l..4l+3)
    for (int i0 = slot; i0 < cnt; i0 += 256) {
        uint2 r[4]; bool v[4];
#pragma unroll
        for (int k = 0; k < 4; ++k) {
            int i = i0 + k * 64;
            v[k] = i < cnt;
            r[k] = v[k] ? rec[e0 + i] : make_uint2(0u, 0u);
        }
        uint2 p[4];
#pragma unroll
        for (int k = 0; k < 4; ++k) {
            int srcn = (int)(r[k].x >> BKT_SH);
            p[k] = v[k] ? xwh[(size_t)srcn * 4 + l] : make_uint2(0u, 0u);
        }
#pragma unroll
        for (int k = 0; k < 4; ++k) {
            float wv = v[k] ? __uint_as_float(r[k].y) : 0.0f;
            int dr = (int)(r[k].x & 127u);
            float2 f01 = __half22float2(*(const __half2*)&p[k].x);
            float2 f23 = __half22float2(*(const __half2*)&p[k].y);
            float* hb = &hloc[dr * HSTRIDE + l * 4];
            atomicAdd(hb + 0, wv * f01.x);
            atomicAdd(hb + 1, wv * f01.y);
            atomicAdd(hb + 2, wv * f23.x);
            atomicAdd(hb + 3, wv * f23.y);
        }
    }
    __syncthreads();
    const int j = t & 15;
    const float b1j = b1[j], w2j = W2[j];
    const int node0 = bkt << BKT_SH;
    for (int n = t >> 4; n < 128; n += 16) {
        int g = node0 + n;
        float vv = fmaxf(hloc[n * HSTRIDE + j] + b1j, 0.0f) * w2j;
        vv += __shfl_xor(vv, 1);
        vv += __shfl_xor(vv, 2);
        vv += __shfl_xor(vv, 4);
        vv += __shfl_xor(vv, 8);
        if (j == 0 && g < N_NODES) hw[g] = vv;
    }
}

// ---------------------------------------------------------------------------
// p5: spmm2 over the same sorted records; 1 lane/edge, 4x unroll.
__global__ __launch_bounds__(256) void p5_layer2(const int* __restrict__ cursor,
                                                 const uint2* __restrict__ rec,
                                                 const float* __restrict__ hw,
                                                 const float* __restrict__ b2,
                                                 float* __restrict__ out, int cap) {
    __shared__ float oloc[128];
    const int t = threadIdx.x;
    const int bkt = blockIdx.x;
    if (t < 128) oloc[t] = 0.0f;
    __syncthreads();
    const int e0 = bkt * cap;
    const int cnt = cursor[bkt] - e0;
    for (int i0 = t; i0 < cnt; i0 += 1024) {
        uint2 r[4]; bool v[4];
#pragma unroll
        for (int k = 0; k < 4; ++k) {
            int i = i0 + k * 256;
            v[k] = i < cnt;
            r[k] = v[k] ? rec[e0 + i] : make_uint2(0u, 0u);
        }
        float hv[4];
#pragma unroll
        for (int k = 0; k < 4; ++k)
            hv[k] = v[k] ? hw[r[k].x >> BKT_SH] : 0.0f;
#pragma unroll
        for (int k = 0; k < 4; ++k)
            atomicAdd(&oloc[r[k].x & 127u], __uint_as_float(r[k].y) * hv[k]);
    }
    __syncthreads();
    if (t < 128) {
        int g = (bkt << BKT_SH) + t;
        if (g < N_NODES) out[g] = b2[0] + oloc[t];
    }
}

// ---------------------------------------------------------------------------
// fallback path (atomic scatter) if workspace is too small
// ---------------------------------------------------------------------------
__global__ void f0_zero(float* __restrict__ h, const float* __restrict__ b2,
                        float* __restrict__ out) {
    int i = blockIdx.x * blockDim.x + threadIdx.x;
    if (i < N_NODES * HID_DIM) h[i] = 0.0f;
    if (i < N_NODES) out[i] = b2[0];
}
__global__ void k2_spmm1(const int* __restrict__ src, const int* __restrict__ dst,
                         const float* __restrict__ wgt, const __half* __restrict__ xwh,
                         float* __restrict__ h) {
    int t = blockIdx.x * blockDim.x + threadIdx.x;
    int e = t >> 4;
    int j = t & (HID_DIM - 1);
    if (e < N_EDGES) {
        float v = wgt[e] * __half2float(xwh[(size_t)src[e] * HID_DIM + j]);
        atomic_add_f32(&h[(size_t)dst[e] * HID_DIM + j], v);
    }
}
__global__ void k3_act(const float* __restrict__ h, const float* __restrict__ b1,
                       const float* __restrict__ W2, float* __restrict__ hw) {
    int i = blockIdx.x * blockDim.x + threadIdx.x;
    if (i >= N_NODES) return;
    const float4* h4 = (const float4*)(h + (size_t)i * HID_DIM);
    const float4* b4 = (const float4*)b1;
    const float4* w4 = (const float4*)W2;
    float acc = 0.0f;
#pragma unroll
    for (int q = 0; q < HID_DIM / 4; ++q) {
        float4 hv = h4[q]; float4 bv = b4[q]; float4 wv = w4[q];
        acc += fmaxf(hv.x + bv.x, 0.0f) * wv.x;
        acc += fmaxf(hv.y + bv.y, 0.0f) * wv.y;
        acc += fmaxf(hv.z + bv.z, 0.0f) * wv.z;
        acc += fmaxf(hv.w + bv.w, 0.0f) * wv.w;
    }
    hw[i] = acc;
}
__global__ void k4_spmm2(const int* __restrict__ src, const int* __restrict__ dst,
                         const float* __restrict__ wgt, const float* __restrict__ hw,
                         float* __restrict__ out) {
    int e = blockIdx.x * blockDim.x + threadIdx.x;
    if (e < N_EDGES) atomic_add_f32(&out[dst[e]], wgt[e] * hw[src[e]]);
}

// ---------------------------------------------------------------------------

extern "C" void kernel_launch(void* const* d_in, const int* in_sizes, int n_in,
                              void* d_out, int out_size, void* d_ws, size_t ws_size,
                              hipStream_t stream) {
    const float* x    = (const float*)d_in[0];
    const int*   esrc = (const int*)  d_in[1];
    const int*   edst = (const int*)  d_in[2];
    const float* ew   = (const float*)d_in[3];
    const float* W1   = (const float*)d_in[4];
    const float* b1   = (const float*)d_in[5];
    const float* W2   = (const float*)d_in[6];
    const float* b2   = (const float*)d_in[7];
    float* out = (float*)d_out;
    char* ws = (char*)d_ws;

    // workspace layout
    __half* xwh   = (__half*)ws;                              // N*16 halfs (3.2MB)
    float*  hw    = (float*)(ws + (size_t)N_NODES * HID_DIM * 2); // N floats
    int*    cursor = (int*)(hw + N_NODES);                    // B_BKT ints
    size_t rec_off = ((size_t)((char*)(cursor + B_BKT) - ws) + 15) & ~(size_t)15;
    uint2* rec = (uint2*)(ws + rec_off);

    int cap = 0;
    if (ws_size > rec_off) {
        size_t cap_fit = (ws_size - rec_off) / ((size_t)B_BKT * sizeof(uint2));
        cap = (int)(cap_fit < CAP_MAX ? cap_fit : CAP_MAX);
    }

    if (cap >= 4480) {
        z0_init<<<(B_BKT + 255) / 256, 256, 0, stream>>>(cursor, cap);
        g1_xw<<<640, 256, 0, stream>>>(x, W1, xwh);
        s1_bin<<<N_EDGES / EPB, 256, 0, stream>>>(esrc, edst, ew, cursor, rec, cap);
        p4_layer1<<<B_BKT, 256, 0, stream>>>(cursor, rec, (const uint2*)xwh, b1, W2, hw, cap);
        p5_layer2<<<B_BKT, 256, 0, stream>>>(cursor, rec, hw, b2, out, cap);
    } else {
        // fallback: atomic scatter
        __half* f_xwh = (__half*)ws;
        float*  f_h   = (float*)(ws + (size_t)N_NODES * HID_DIM * 2);
        float*  f_hw  = f_h + (size_t)N_NODES * HID_DIM;
        int n = N_NODES * HID_DIM;
        f0_zero<<<(n + 255) / 256, 256, 0, stream>>>(f_h, b2, out);
        g1_xw<<<640, 256, 0, stream>>>(x, W1, f_xwh);
        k2_spmm1<<<(N_EDGES * 16) / 256, 256, 0, stream>>>(esrc, edst, ew, f_xwh, f_h);
        k3_act<<<(N_NODES + 255) / 256, 256, 0, stream>>>(f_h, b1, W2, f_hw);
        k4_spmm2<<<(N_EDGES + 255) / 256, 256, 0, stream>>>(esrc, edst, ew, f_hw, out);
    }
}

// Round 5
// 504.140 us; speedup vs baseline: 2.1418x; 1.5980x over previous
//
#include <hip/hip_runtime.h>
#include <hip/hip_fp16.h>

#define N_NODES 100000
#define N_EDGES 3200000
#define IN_DIM  512
#define HID_DIM 16

#define B_BKT   782      // ceil(100000 / 128) buckets of 128 nodes
#define BKT_SH  7        // bucket = dst >> 7, dstrel = dst & 127
#define EPB     12500    // edges per s1 block (256 blocks * 12500 = 3.2M)
#define CAP_MAX 4608     // per-bucket record capacity (mean 4093 + ~8 sigma)

__device__ __forceinline__ void atomic_add_f32(float* p, float v) {
    __hip_atomic_fetch_add(p, v, __ATOMIC_RELAXED, __HIP_MEMORY_SCOPE_AGENT);
}
__device__ __forceinline__ int atomic_add_i32(int* p, int v) {
    return __hip_atomic_fetch_add(p, v, __ATOMIC_RELAXED, __HIP_MEMORY_SCOPE_AGENT);
}

// ---------------------------------------------------------------------------
__global__ void z0_init(int* __restrict__ cursor, int cap) {
    int b = blockIdx.x * blockDim.x + threadIdx.x;
    if (b < B_BKT) cursor[b] = b * cap;
}

// ---------------------------------------------------------------------------
// g1: xw = x @ W1 -> fp16. One wave per row; W1 fragment in 128 VGPRs;
// x reads are two fully-coalesced dwordx4 per row.
__global__ __launch_bounds__(256) void g1_xw(const float* __restrict__ x,
                                             const float* __restrict__ W1,
                                             __half* __restrict__ xwh) {
    const int lane  = threadIdx.x & 63;
    const int wave  = (blockIdx.x * blockDim.x + threadIdx.x) >> 6;
    const int nwave = (gridDim.x * blockDim.x) >> 6;

    float w[8][16];
#pragma unroll
    for (int q = 0; q < 8; ++q) {
        int k = (q < 4) ? (lane * 4 + q) : (256 + lane * 4 + (q - 4));
        const float4* wr = (const float4*)(W1 + (size_t)k * HID_DIM);
        float4 a = wr[0], b = wr[1], c = wr[2], d = wr[3];
        w[q][0]=a.x; w[q][1]=a.y; w[q][2]=a.z; w[q][3]=a.w;
        w[q][4]=b.x; w[q][5]=b.y; w[q][6]=b.z; w[q][7]=b.w;
        w[q][8]=c.x; w[q][9]=c.y; w[q][10]=c.z; w[q][11]=c.w;
        w[q][12]=d.x; w[q][13]=d.y; w[q][14]=d.z; w[q][15]=d.w;
    }

    const float4* x4 = (const float4*)x;
    int row = wave;
    float4 xa, xb;
    if (row < N_NODES) {
        xa = x4[(size_t)row * 128 + lane];
        xb = x4[(size_t)row * 128 + 64 + lane];
    }
    while (row < N_NODES) {
        int nrow = row + nwave;
        float4 na, nb;
        if (nrow < N_NODES) {
            na = x4[(size_t)nrow * 128 + lane];
            nb = x4[(size_t)nrow * 128 + 64 + lane];
        }
        float acc[16];
#pragma unroll
        for (int j = 0; j < 16; ++j) {
            acc[j] = xa.x * w[0][j] + xa.y * w[1][j] + xa.z * w[2][j] + xa.w * w[3][j]
                   + xb.x * w[4][j] + xb.y * w[5][j] + xb.z * w[6][j] + xb.w * w[7][j];
        }
#pragma unroll
        for (int j = 0; j < 16; ++j) {
            acc[j] += __shfl_xor(acc[j], 32);
            acc[j] += __shfl_xor(acc[j], 16);
        }
        float c8[8];
#pragma unroll
        for (int i = 0; i < 8; ++i) {
            bool hi = (lane & 8) != 0;
            float keep = hi ? acc[i + 8] : acc[i];
            float send = hi ? acc[i] : acc[i + 8];
            c8[i] = keep + __shfl_xor(send, 8);
        }
        float c4[4];
#pragma unroll
        for (int i = 0; i < 4; ++i) {
            bool hi = (lane & 4) != 0;
            float keep = hi ? c8[i + 4] : c8[i];
            float send = hi ? c8[i] : c8[i + 4];
            c4[i] = keep + __shfl_xor(send, 4);
        }
        float c2[2];
#pragma unroll
        for (int i = 0; i < 2; ++i) {
            bool hi = (lane & 2) != 0;
            float keep = hi ? c4[i + 2] : c4[i];
            float send = hi ? c4[i] : c4[i + 2];
            c2[i] = keep + __shfl_xor(send, 2);
        }
        {
            bool hi = (lane & 1) != 0;
            float keep = hi ? c2[1] : c2[0];
            float send = hi ? c2[0] : c2[1];
            float c1 = keep + __shfl_xor(send, 1);
            if (lane < 16) xwh[(size_t)row * HID_DIM + lane] = __float2half_rn(c1);
        }
        row = nrow; xa = na; xb = nb;
    }
}

// ---------------------------------------------------------------------------
// s1: counting-sort edges into coarse bucket regions, block-batched runs.
__global__ __launch_bounds__(256) void s1_bin(const int* __restrict__ src,
                                              const int* __restrict__ dst,
                                              const float* __restrict__ wgt,
                                              int* __restrict__ cursor,
                                              uint2* __restrict__ rec, int cap) {
    __shared__ int hist[B_BKT];
    __shared__ int base[B_BKT];
    const int t = threadIdx.x;
    for (int b = t; b < B_BKT; b += 256) hist[b] = 0;
    __syncthreads();
    const int e0 = blockIdx.x * EPB;
    const int4*   d4 = (const int4*)(dst + e0);
    const int4*   s4 = (const int4*)(src + e0);
    const float4* w4 = (const float4*)(wgt + e0);
    const int NG = EPB / 4;
    for (int g = t; g < NG; g += 256) {
        int4 d = d4[g];
        atomicAdd(&hist[d.x >> BKT_SH], 1);
        atomicAdd(&hist[d.y >> BKT_SH], 1);
        atomicAdd(&hist[d.z >> BKT_SH], 1);
        atomicAdd(&hist[d.w >> BKT_SH], 1);
    }
    __syncthreads();
    for (int b = t; b < B_BKT; b += 256) {
        int c = hist[b];
        base[b] = c > 0 ? atomic_add_i32(&cursor[b], c) : 0;
    }
    __syncthreads();
    for (int b = t; b < B_BKT; b += 256) hist[b] = 0;
    __syncthreads();
    for (int g = t; g < NG; g += 256) {
        int4 d = d4[g];
        int4 s = s4[g];
        float4 w = w4[g];
        {
            int b = d.x >> BKT_SH;
            int pos = base[b] + atomicAdd(&hist[b], 1);
            rec[pos] = make_uint2(((unsigned)s.x << BKT_SH) | (unsigned)(d.x & 127),
                                  __float_as_uint(w.x));
        }
        {
            int b = d.y >> BKT_SH;
            int pos = base[b] + atomicAdd(&hist[b], 1);
            rec[pos] = make_uint2(((unsigned)s.y << BKT_SH) | (unsigned)(d.y & 127),
                                  __float_as_uint(w.y));
        }
        {
            int b = d.z >> BKT_SH;
            int pos = base[b] + atomicAdd(&hist[b], 1);
            rec[pos] = make_uint2(((unsigned)s.z << BKT_SH) | (unsigned)(d.z & 127),
                                  __float_as_uint(w.z));
        }
        {
            int b = d.w >> BKT_SH;
            int pos = base[b] + atomicAdd(&hist[b], 1);
            rec[pos] = make_uint2(((unsigned)s.w << BKT_SH) | (unsigned)(d.w & 127),
                                  __float_as_uint(w.w));
        }
    }
}

// ---------------------------------------------------------------------------
// s2: per-bucket counting sort by dstrel, IN PLACE (recs staged in LDS first).
// Emits row[node] = (segment begin, degree) and strips dstrel from records
// (rec becomes (src, w) sorted by dst).
__global__ __launch_bounds__(256) void s2_sort(const int* __restrict__ cursor,
                                               uint2* __restrict__ rec,
                                               int2* __restrict__ row, int cap) {
    __shared__ uint2 srec[CAP_MAX];
    __shared__ int ocnt[128], scn[128], cur[128];
    const int t = threadIdx.x;
    const int bkt = blockIdx.x;
    const int e0 = bkt * cap;
    int n = cursor[bkt] - e0;
    n = max(0, min(n, cap));
    if (t < 128) ocnt[t] = 0;
    __syncthreads();
    for (int i = t; i < n; i += 256) {
        uint2 r = rec[e0 + i];
        srec[i] = r;
        atomicAdd(&ocnt[r.x & 127u], 1);
    }
    __syncthreads();
    if (t < 128) scn[t] = ocnt[t];
    __syncthreads();
    for (int off = 1; off < 128; off <<= 1) {
        int v = 0;
        if (t < 128 && t >= off) v = scn[t - off];
        __syncthreads();
        if (t < 128 && t >= off) scn[t] += v;
        __syncthreads();
    }
    if (t < 128) {
        int b = scn[t] - ocnt[t];          // exclusive prefix
        cur[t] = b;
        int node = (bkt << BKT_SH) + t;
        if (node < N_NODES) row[node] = make_int2(e0 + b, ocnt[t]);
    }
    __syncthreads();
    for (int i = t; i < n; i += 256) {
        uint2 r = srec[i];
        int d = (int)(r.x & 127u);
        int pos = atomicAdd(&cur[d], 1);
        rec[e0 + pos] = make_uint2(r.x >> BKT_SH, r.y);   // (src, w)
    }
}

// ---------------------------------------------------------------------------
// p4: fused spmm1 + bias + relu + (.W2). 16 lanes per node, lane j owns dim j.
// Register accumulation, no atomics. rec loads broadcast; xwh gather is one
// 32B line per (node-group, edge). Unroll 4 for MLP.
__global__ __launch_bounds__(256) void p4_layer1(const int2* __restrict__ row,
                                                 const uint2* __restrict__ rec,
                                                 const __half* __restrict__ xwh,
                                                 const float* __restrict__ b1,
                                                 const float* __restrict__ W2,
                                                 float* __restrict__ hw) {
    const int t = threadIdx.x;
    const int node = blockIdx.x * 16 + (t >> 4);
    const int j = t & 15;
    int2 r = row[node];
    int e = r.x;
    const int end = r.x + r.y;
    float acc = 0.0f;
    for (; e + 4 <= end; e += 4) {
        uint2 q0 = rec[e], q1 = rec[e + 1], q2 = rec[e + 2], q3 = rec[e + 3];
        float f0 = __half2float(xwh[(size_t)q0.x * HID_DIM + j]);
        float f1 = __half2float(xwh[(size_t)q1.x * HID_DIM + j]);
        float f2 = __half2float(xwh[(size_t)q2.x * HID_DIM + j]);
        float f3 = __half2float(xwh[(size_t)q3.x * HID_DIM + j]);
        acc += __uint_as_float(q0.y) * f0;
        acc += __uint_as_float(q1.y) * f1;
        acc += __uint_as_float(q2.y) * f2;
        acc += __uint_as_float(q3.y) * f3;
    }
    for (; e < end; ++e) {
        uint2 q = rec[e];
        acc += __uint_as_float(q.y) * __half2float(xwh[(size_t)q.x * HID_DIM + j]);
    }
    float v = fmaxf(acc + b1[j], 0.0f) * W2[j];
    v += __shfl_xor(v, 1);
    v += __shfl_xor(v, 2);
    v += __shfl_xor(v, 4);
    v += __shfl_xor(v, 8);
    if (j == 0) hw[node] = v;
}

// ---------------------------------------------------------------------------
// p5: spmm2 over the same sorted records; 8 lanes/node, coalesced rec reads,
// register accumulation, no atomics.
__global__ __launch_bounds__(256) void p5_layer2(const int2* __restrict__ row,
                                                 const uint2* __restrict__ rec,
                                                 const float* __restrict__ hwv,
                                                 const float* __restrict__ b2,
                                                 float* __restrict__ out) {
    const int t = threadIdx.x;
    const int node = blockIdx.x * 32 + (t >> 3);
    const int i = t & 7;
    int2 r = row[node];
    const int end = r.x + r.y;
    int k = r.x + i;
    float s = 0.0f;
    for (; k + 24 < end; k += 32) {
        uint2 a = rec[k], b = rec[k + 8], c = rec[k + 16], d = rec[k + 24];
        float ha = hwv[a.x], hb = hwv[b.x], hc = hwv[c.x], hd = hwv[d.x];
        s += __uint_as_float(a.y) * ha + __uint_as_float(b.y) * hb
           + __uint_as_float(c.y) * hc + __uint_as_float(d.y) * hd;
    }
    for (; k < end; k += 8) {
        uint2 a = rec[k];
        s += __uint_as_float(a.y) * hwv[a.x];
    }
    s += __shfl_xor(s, 1);
    s += __shfl_xor(s, 2);
    s += __shfl_xor(s, 4);
    if (i == 0) out[node] = b2[0] + s;
}

// ---------------------------------------------------------------------------
// fallback path (atomic scatter) if workspace is too small
// ---------------------------------------------------------------------------
__global__ void f0_zero(float* __restrict__ h, const float* __restrict__ b2,
                        float* __restrict__ out) {
    int i = blockIdx.x * blockDim.x + threadIdx.x;
    if (i < N_NODES * HID_DIM) h[i] = 0.0f;
    if (i < N_NODES) out[i] = b2[0];
}
__global__ void k2_spmm1(const int* __restrict__ src, const int* __restrict__ dst,
                         const float* __restrict__ wgt, const __half* __restrict__ xwh,
                         float* __restrict__ h) {
    int t = blockIdx.x * blockDim.x + threadIdx.x;
    int e = t >> 4;
    int j = t & (HID_DIM - 1);
    if (e < N_EDGES) {
        float v = wgt[e] * __half2float(xwh[(size_t)src[e] * HID_DIM + j]);
        atomic_add_f32(&h[(size_t)dst[e] * HID_DIM + j], v);
    }
}
__global__ void k3_act(const float* __restrict__ h, const float* __restrict__ b1,
                       const float* __restrict__ W2, float* __restrict__ hw) {
    int i = blockIdx.x * blockDim.x + threadIdx.x;
    if (i >= N_NODES) return;
    const float4* h4 = (const float4*)(h + (size_t)i * HID_DIM);
    const float4* b4 = (const float4*)b1;
    const float4* w4 = (const float4*)W2;
    float acc = 0.0f;
#pragma unroll
    for (int q = 0; q < HID_DIM / 4; ++q) {
        float4 hv = h4[q]; float4 bv = b4[q]; float4 wv = w4[q];
        acc += fmaxf(hv.x + bv.x, 0.0f) * wv.x;
        acc += fmaxf(hv.y + bv.y, 0.0f) * wv.y;
        acc += fmaxf(hv.z + bv.z, 0.0f) * wv.z;
        acc += fmaxf(hv.w + bv.w, 0.0f) * wv.w;
    }
    hw[i] = acc;
}
__global__ void k4_spmm2(const int* __restrict__ src, const int* __restrict__ dst,
                         const float* __restrict__ wgt, const float* __restrict__ hw,
                         float* __restrict__ out) {
    int e = blockIdx.x * blockDim.x + threadIdx.x;
    if (e < N_EDGES) atomic_add_f32(&out[dst[e]], wgt[e] * hw[src[e]]);
}

// ---------------------------------------------------------------------------

extern "C" void kernel_launch(void* const* d_in, const int* in_sizes, int n_in,
                              void* d_out, int out_size, void* d_ws, size_t ws_size,
                              hipStream_t stream) {
    const float* x    = (const float*)d_in[0];
    const int*   esrc = (const int*)  d_in[1];
    const int*   edst = (const int*)  d_in[2];
    const float* ew   = (const float*)d_in[3];
    const float* W1   = (const float*)d_in[4];
    const float* b1   = (const float*)d_in[5];
    const float* W2   = (const float*)d_in[6];
    const float* b2   = (const float*)d_in[7];
    float* out = (float*)d_out;
    char* ws = (char*)d_ws;

    // workspace layout
    __half* xwh    = (__half*)ws;                                  // N*16 halfs
    float*  hw     = (float*)(ws + (size_t)N_NODES * HID_DIM * 2); // N floats
    int*    cursor = (int*)(hw + N_NODES);                         // B_BKT ints
    int2*   row    = (int2*)(((size_t)(cursor + B_BKT) + 7) & ~(size_t)7); // N int2
    size_t rec_off = ((size_t)((char*)(row + N_NODES) - ws) + 15) & ~(size_t)15;
    uint2* rec = (uint2*)(ws + rec_off);

    int cap = 0;
    if (ws_size > rec_off) {
        size_t cap_fit = (ws_size - rec_off) / ((size_t)B_BKT * sizeof(uint2));
        cap = (int)(cap_fit < CAP_MAX ? cap_fit : CAP_MAX);
    }

    if (cap >= 4480) {
        z0_init<<<(B_BKT + 255) / 256, 256, 0, stream>>>(cursor, cap);
        g1_xw<<<640, 256, 0, stream>>>(x, W1, xwh);
        s1_bin<<<N_EDGES / EPB, 256, 0, stream>>>(esrc, edst, ew, cursor, rec, cap);
        s2_sort<<<B_BKT, 256, 0, stream>>>(cursor, rec, row, cap);
        p4_layer1<<<N_NODES / 16, 256, 0, stream>>>(row, rec, xwh, b1, W2, hw);
        p5_layer2<<<N_NODES / 32, 256, 0, stream>>>(row, rec, hw, b2, out);
    } else {
        // fallback: atomic scatter
        __half* f_xwh = (__half*)ws;
        float*  f_h   = (float*)(ws + (size_t)N_NODES * HID_DIM * 2);
        float*  f_hw  = f_h + (size_t)N_NODES * HID_DIM;
        int n = N_NODES * HID_DIM;
        f0_zero<<<(n + 255) / 256, 256, 0, stream>>>(f_h, b2, out);
        g1_xw<<<640, 256, 0, stream>>>(x, W1, f_xwh);
        k2_spmm1<<<(N_EDGES * 16) / 256, 256, 0, stream>>>(esrc, edst, ew, f_xwh, f_h);
        k3_act<<<(N_NODES + 255) / 256, 256, 0, stream>>>(f_h, b1, W2, f_hw);
        k4_spmm2<<<(N_EDGES + 255) / 256, 256, 0, stream>>>(esrc, edst, ew, f_hw, out);
    }
}

// Round 6
// 480.723 us; speedup vs baseline: 2.2461x; 1.0487x over previous
//
#include <hip/hip_runtime.h>
#include <hip/hip_fp16.h>

#define N_NODES 100000
#define N_EDGES 3200000
#define IN_DIM  512
#define HID_DIM 16

#define B_BKT   782      // ceil(100000 / 128) buckets of 128 nodes
#define BKT_SH  7        // bucket = dst >> 7, dstrel = dst & 127
#define EPB     12500    // edges per s1 block (256 blocks * 12500 = 3.2M)
#define CAP_MAX 4608     // per-bucket record capacity (mean 4093 + ~8 sigma)

__device__ __forceinline__ void atomic_add_f32(float* p, float v) {
    __hip_atomic_fetch_add(p, v, __ATOMIC_RELAXED, __HIP_MEMORY_SCOPE_AGENT);
}
__device__ __forceinline__ int atomic_add_i32(int* p, int v) {
    return __hip_atomic_fetch_add(p, v, __ATOMIC_RELAXED, __HIP_MEMORY_SCOPE_AGENT);
}

// ---------------------------------------------------------------------------
__global__ void z0_init(int* __restrict__ cursor, int cap) {
    int b = blockIdx.x * blockDim.x + threadIdx.x;
    if (b < B_BKT) cursor[b] = b * cap;
}

// ---------------------------------------------------------------------------
// g1: xw = x @ W1 -> fp16. One wave per row; W1 fragment in 128 VGPRs;
// x reads are two fully-coalesced dwordx4 per row.
// Grid 3125 blocks = 12500 waves: 5 waves/SIMD resident (VGPR-capped) for
// latency hiding — 640 blocks left the kernel 4x over the memory floor.
__global__ __launch_bounds__(256) void g1_xw(const float* __restrict__ x,
                                             const float* __restrict__ W1,
                                             __half* __restrict__ xwh) {
    const int lane  = threadIdx.x & 63;
    const int wave  = (blockIdx.x * blockDim.x + threadIdx.x) >> 6;
    const int nwave = (gridDim.x * blockDim.x) >> 6;

    float w[8][16];
#pragma unroll
    for (int q = 0; q < 8; ++q) {
        int k = (q < 4) ? (lane * 4 + q) : (256 + lane * 4 + (q - 4));
        const float4* wr = (const float4*)(W1 + (size_t)k * HID_DIM);
        float4 a = wr[0], b = wr[1], c = wr[2], d = wr[3];
        w[q][0]=a.x; w[q][1]=a.y; w[q][2]=a.z; w[q][3]=a.w;
        w[q][4]=b.x; w[q][5]=b.y; w[q][6]=b.z; w[q][7]=b.w;
        w[q][8]=c.x; w[q][9]=c.y; w[q][10]=c.z; w[q][11]=c.w;
        w[q][12]=d.x; w[q][13]=d.y; w[q][14]=d.z; w[q][15]=d.w;
    }

    const float4* x4 = (const float4*)x;
    int row = wave;
    float4 xa, xb;
    if (row < N_NODES) {
        xa = x4[(size_t)row * 128 + lane];
        xb = x4[(size_t)row * 128 + 64 + lane];
    }
    while (row < N_NODES) {
        int nrow = row + nwave;
        float4 na, nb;
        if (nrow < N_NODES) {
            na = x4[(size_t)nrow * 128 + lane];
            nb = x4[(size_t)nrow * 128 + 64 + lane];
        }
        float acc[16];
#pragma unroll
        for (int j = 0; j < 16; ++j) {
            acc[j] = xa.x * w[0][j] + xa.y * w[1][j] + xa.z * w[2][j] + xa.w * w[3][j]
                   + xb.x * w[4][j] + xb.y * w[5][j] + xb.z * w[6][j] + xb.w * w[7][j];
        }
#pragma unroll
        for (int j = 0; j < 16; ++j) {
            acc[j] += __shfl_xor(acc[j], 32);
            acc[j] += __shfl_xor(acc[j], 16);
        }
        float c8[8];
#pragma unroll
        for (int i = 0; i < 8; ++i) {
            bool hi = (lane & 8) != 0;
            float keep = hi ? acc[i + 8] : acc[i];
            float send = hi ? acc[i] : acc[i + 8];
            c8[i] = keep + __shfl_xor(send, 8);
        }
        float c4[4];
#pragma unroll
        for (int i = 0; i < 4; ++i) {
            bool hi = (lane & 4) != 0;
            float keep = hi ? c8[i + 4] : c8[i];
            float send = hi ? c8[i] : c8[i + 4];
            c4[i] = keep + __shfl_xor(send, 4);
        }
        float c2[2];
#pragma unroll
        for (int i = 0; i < 2; ++i) {
            bool hi = (lane & 2) != 0;
            float keep = hi ? c4[i + 2] : c4[i];
            float send = hi ? c4[i] : c4[i + 2];
            c2[i] = keep + __shfl_xor(send, 2);
        }
        {
            bool hi = (lane & 1) != 0;
            float keep = hi ? c2[1] : c2[0];
            float send = hi ? c2[0] : c2[1];
            float c1 = keep + __shfl_xor(send, 1);
            if (lane < 16) xwh[(size_t)row * HID_DIM + lane] = __float2half_rn(c1);
        }
        row = nrow; xa = na; xb = nb;
    }
}

// ---------------------------------------------------------------------------
// s1: counting-sort edges into coarse bucket regions, block-batched runs.
// 1024 threads (was 256): 4x the resident waves during the latency-bound
// scatter phase; 256 blocks kept so write-runs stay ~16 recs (128B) long.
__global__ __launch_bounds__(1024) void s1_bin(const int* __restrict__ src,
                                               const int* __restrict__ dst,
                                               const float* __restrict__ wgt,
                                               int* __restrict__ cursor,
                                               uint2* __restrict__ rec, int cap) {
    __shared__ int hist[B_BKT];
    __shared__ int base[B_BKT];
    const int t = threadIdx.x;
    for (int b = t; b < B_BKT; b += 1024) hist[b] = 0;
    __syncthreads();
    const int e0 = blockIdx.x * EPB;
    const int4*   d4 = (const int4*)(dst + e0);
    const int4*   s4 = (const int4*)(src + e0);
    const float4* w4 = (const float4*)(wgt + e0);
    const int NG = EPB / 4;
    for (int g = t; g < NG; g += 1024) {
        int4 d = d4[g];
        atomicAdd(&hist[d.x >> BKT_SH], 1);
        atomicAdd(&hist[d.y >> BKT_SH], 1);
        atomicAdd(&hist[d.z >> BKT_SH], 1);
        atomicAdd(&hist[d.w >> BKT_SH], 1);
    }
    __syncthreads();
    for (int b = t; b < B_BKT; b += 1024) {
        int c = hist[b];
        base[b] = c > 0 ? atomic_add_i32(&cursor[b], c) : 0;
    }
    __syncthreads();
    for (int b = t; b < B_BKT; b += 1024) hist[b] = 0;
    __syncthreads();
    for (int g = t; g < NG; g += 1024) {
        int4 d = d4[g];
        int4 s = s4[g];
        float4 w = w4[g];
        {
            int b = d.x >> BKT_SH;
            int pos = base[b] + atomicAdd(&hist[b], 1);
            rec[pos] = make_uint2(((unsigned)s.x << BKT_SH) | (unsigned)(d.x & 127),
                                  __float_as_uint(w.x));
        }
        {
            int b = d.y >> BKT_SH;
            int pos = base[b] + atomicAdd(&hist[b], 1);
            rec[pos] = make_uint2(((unsigned)s.y << BKT_SH) | (unsigned)(d.y & 127),
                                  __float_as_uint(w.y));
        }
        {
            int b = d.z >> BKT_SH;
            int pos = base[b] + atomicAdd(&hist[b], 1);
            rec[pos] = make_uint2(((unsigned)s.z << BKT_SH) | (unsigned)(d.z & 127),
                                  __float_as_uint(w.z));
        }
        {
            int b = d.w >> BKT_SH;
            int pos = base[b] + atomicAdd(&hist[b], 1);
            rec[pos] = make_uint2(((unsigned)s.w << BKT_SH) | (unsigned)(d.w & 127),
                                  __float_as_uint(w.w));
        }
    }
}

// ---------------------------------------------------------------------------
// s2: per-bucket counting sort by dstrel, IN PLACE (recs staged in LDS).
// Emits row[node] = (segment begin, degree); rec becomes (src, w) by dst.
// 512 threads (was 256) to halve the serial staging loops.
__global__ __launch_bounds__(512) void s2_sort(const int* __restrict__ cursor,
                                               uint2* __restrict__ rec,
                                               int2* __restrict__ row, int cap) {
    __shared__ uint2 srec[CAP_MAX];
    __shared__ int ocnt[128], scn[128], cur[128];
    const int t = threadIdx.x;
    const int bkt = blockIdx.x;
    const int e0 = bkt * cap;
    int n = cursor[bkt] - e0;
    n = max(0, min(n, cap));
    if (t < 128) ocnt[t] = 0;
    __syncthreads();
    for (int i = t; i < n; i += 512) {
        uint2 r = rec[e0 + i];
        srec[i] = r;
        atomicAdd(&ocnt[r.x & 127u], 1);
    }
    __syncthreads();
    if (t < 128) scn[t] = ocnt[t];
    __syncthreads();
    for (int off = 1; off < 128; off <<= 1) {
        int v = 0;
        if (t < 128 && t >= off) v = scn[t - off];
        __syncthreads();
        if (t < 128 && t >= off) scn[t] += v;
        __syncthreads();
    }
    if (t < 128) {
        int b = scn[t] - ocnt[t];          // exclusive prefix
        cur[t] = b;
        int node = (bkt << BKT_SH) + t;
        if (node < N_NODES) row[node] = make_int2(e0 + b, ocnt[t]);
    }
    __syncthreads();
    for (int i = t; i < n; i += 512) {
        uint2 r = srec[i];
        int d = (int)(r.x & 127u);
        int pos = atomicAdd(&cur[d], 1);
        rec[e0 + pos] = make_uint2(r.x >> BKT_SH, r.y);   // (src, w)
    }
}

// ---------------------------------------------------------------------------
// p4: fused spmm1 + bias + relu + (.W2). 16 lanes per node, lane j owns dim j.
// Register accumulation, no atomics.
__global__ __launch_bounds__(256) void p4_layer1(const int2* __restrict__ row,
                                                 const uint2* __restrict__ rec,
                                                 const __half* __restrict__ xwh,
                                                 const float* __restrict__ b1,
                                                 const float* __restrict__ W2,
                                                 float* __restrict__ hw) {
    const int t = threadIdx.x;
    const int node = blockIdx.x * 16 + (t >> 4);
    const int j = t & 15;
    int2 r = row[node];
    int e = r.x;
    const int end = r.x + r.y;
    float acc = 0.0f;
    for (; e + 4 <= end; e += 4) {
        uint2 q0 = rec[e], q1 = rec[e + 1], q2 = rec[e + 2], q3 = rec[e + 3];
        float f0 = __half2float(xwh[(size_t)q0.x * HID_DIM + j]);
        float f1 = __half2float(xwh[(size_t)q1.x * HID_DIM + j]);
        float f2 = __half2float(xwh[(size_t)q2.x * HID_DIM + j]);
        float f3 = __half2float(xwh[(size_t)q3.x * HID_DIM + j]);
        acc += __uint_as_float(q0.y) * f0;
        acc += __uint_as_float(q1.y) * f1;
        acc += __uint_as_float(q2.y) * f2;
        acc += __uint_as_float(q3.y) * f3;
    }
    for (; e < end; ++e) {
        uint2 q = rec[e];
        acc += __uint_as_float(q.y) * __half2float(xwh[(size_t)q.x * HID_DIM + j]);
    }
    float v = fmaxf(acc + b1[j], 0.0f) * W2[j];
    v += __shfl_xor(v, 1);
    v += __shfl_xor(v, 2);
    v += __shfl_xor(v, 4);
    v += __shfl_xor(v, 8);
    if (j == 0) hw[node] = v;
}

// ---------------------------------------------------------------------------
// p5: spmm2 over the same sorted records; 8 lanes/node, coalesced rec reads.
__global__ __launch_bounds__(256) void p5_layer2(const int2* __restrict__ row,
                                                 const uint2* __restrict__ rec,
                                                 const float* __restrict__ hwv,
                                                 const float* __restrict__ b2,
                                                 float* __restrict__ out) {
    const int t = threadIdx.x;
    const int node = blockIdx.x * 32 + (t >> 3);
    const int i = t & 7;
    int2 r = row[node];
    const int end = r.x + r.y;
    int k = r.x + i;
    float s = 0.0f;
    for (; k + 24 < end; k += 32) {
        uint2 a = rec[k], b = rec[k + 8], c = rec[k + 16], d = rec[k + 24];
        float ha = hwv[a.x], hb = hwv[b.x], hc = hwv[c.x], hd = hwv[d.x];
        s += __uint_as_float(a.y) * ha + __uint_as_float(b.y) * hb
           + __uint_as_float(c.y) * hc + __uint_as_float(d.y) * hd;
    }
    for (; k < end; k += 8) {
        uint2 a = rec[k];
        s += __uint_as_float(a.y) * hwv[a.x];
    }
    s += __shfl_xor(s, 1);
    s += __shfl_xor(s, 2);
    s += __shfl_xor(s, 4);
    if (i == 0) out[node] = b2[0] + s;
}

// ---------------------------------------------------------------------------
// fallback path (atomic scatter) if workspace is too small
// ---------------------------------------------------------------------------
__global__ void f0_zero(float* __restrict__ h, const float* __restrict__ b2,
                        float* __restrict__ out) {
    int i = blockIdx.x * blockDim.x + threadIdx.x;
    if (i < N_NODES * HID_DIM) h[i] = 0.0f;
    if (i < N_NODES) out[i] = b2[0];
}
__global__ void k2_spmm1(const int* __restrict__ src, const int* __restrict__ dst,
                         const float* __restrict__ wgt, const __half* __restrict__ xwh,
                         float* __restrict__ h) {
    int t = blockIdx.x * blockDim.x + threadIdx.x;
    int e = t >> 4;
    int j = t & (HID_DIM - 1);
    if (e < N_EDGES) {
        float v = wgt[e] * __half2float(xwh[(size_t)src[e] * HID_DIM + j]);
        atomic_add_f32(&h[(size_t)dst[e] * HID_DIM + j], v);
    }
}
__global__ void k3_act(const float* __restrict__ h, const float* __restrict__ b1,
                       const float* __restrict__ W2, float* __restrict__ hw) {
    int i = blockIdx.x * blockDim.x + threadIdx.x;
    if (i >= N_NODES) return;
    const float4* h4 = (const float4*)(h + (size_t)i * HID_DIM);
    const float4* b4 = (const float4*)b1;
    const float4* w4 = (const float4*)W2;
    float acc = 0.0f;
#pragma unroll
    for (int q = 0; q < HID_DIM / 4; ++q) {
        float4 hv = h4[q]; float4 bv = b4[q]; float4 wv = w4[q];
        acc += fmaxf(hv.x + bv.x, 0.0f) * wv.x;
        acc += fmaxf(hv.y + bv.y, 0.0f) * wv.y;
        acc += fmaxf(hv.z + bv.z, 0.0f) * wv.z;
        acc += fmaxf(hv.w + bv.w, 0.0f) * wv.w;
    }
    hw[i] = acc;
}
__global__ void k4_spmm2(const int* __restrict__ src, const int* __restrict__ dst,
                         const float* __restrict__ wgt, const float* __restrict__ hw,
                         float* __restrict__ out) {
    int e = blockIdx.x * blockDim.x + threadIdx.x;
    if (e < N_EDGES) atomic_add_f32(&out[dst[e]], wgt[e] * hw[src[e]]);
}

// ---------------------------------------------------------------------------

extern "C" void kernel_launch(void* const* d_in, const int* in_sizes, int n_in,
                              void* d_out, int out_size, void* d_ws, size_t ws_size,
                              hipStream_t stream) {
    const float* x    = (const float*)d_in[0];
    const int*   esrc = (const int*)  d_in[1];
    const int*   edst = (const int*)  d_in[2];
    const float* ew   = (const float*)d_in[3];
    const float* W1   = (const float*)d_in[4];
    const float* b1   = (const float*)d_in[5];
    const float* W2   = (const float*)d_in[6];
    const float* b2   = (const float*)d_in[7];
    float* out = (float*)d_out;
    char* ws = (char*)d_ws;

    // workspace layout
    __half* xwh    = (__half*)ws;                                  // N*16 halfs
    float*  hw     = (float*)(ws + (size_t)N_NODES * HID_DIM * 2); // N floats
    int*    cursor = (int*)(hw + N_NODES);                         // B_BKT ints
    int2*   row    = (int2*)(((size_t)(cursor + B_BKT) + 7) & ~(size_t)7); // N int2
    size_t rec_off = ((size_t)((char*)(row + N_NODES) - ws) + 15) & ~(size_t)15;
    uint2* rec = (uint2*)(ws + rec_off);

    int cap = 0;
    if (ws_size > rec_off) {
        size_t cap_fit = (ws_size - rec_off) / ((size_t)B_BKT * sizeof(uint2));
        cap = (int)(cap_fit < CAP_MAX ? cap_fit : CAP_MAX);
    }

    if (cap >= 4480) {
        z0_init<<<(B_BKT + 255) / 256, 256, 0, stream>>>(cursor, cap);
        g1_xw<<<3125, 256, 0, stream>>>(x, W1, xwh);
        s1_bin<<<N_EDGES / EPB, 1024, 0, stream>>>(esrc, edst, ew, cursor, rec, cap);
        s2_sort<<<B_BKT, 512, 0, stream>>>(cursor, rec, row, cap);
        p4_layer1<<<N_NODES / 16, 256, 0, stream>>>(row, rec, xwh, b1, W2, hw);
        p5_layer2<<<N_NODES / 32, 256, 0, stream>>>(row, rec, hw, b2, out);
    } else {
        // fallback: atomic scatter
        __half* f_xwh = (__half*)ws;
        float*  f_h   = (float*)(ws + (size_t)N_NODES * HID_DIM * 2);
        float*  f_hw  = f_h + (size_t)N_NODES * HID_DIM;
        int n = N_NODES * HID_DIM;
        f0_zero<<<(n + 255) / 256, 256, 0, stream>>>(f_h, b2, out);
        g1_xw<<<3125, 256, 0, stream>>>(x, W1, f_xwh);
        k2_spmm1<<<(N_EDGES * 16) / 256, 256, 0, stream>>>(esrc, edst, ew, f_xwh, f_h);
        k3_act<<<(N_NODES + 255) / 256, 256, 0, stream>>>(f_h, b1, W2, f_hw);
        k4_spmm2<<<(N_EDGES + 255) / 256, 256, 0, stream>>>(esrc, edst, ew, f_hw, out);
    }
}